// Round 9
// baseline (160.588 us; speedup 1.0000x reference)
//
#include <hip/hip_runtime.h>

#define N_DIM 32
#define NPB 64               // fine bucket: nodes per bucket
#define NPB_SHIFT 6
#define NB_MAX 2048          // max fine buckets (n_nodes <= 131072)
#define NC_MAX 128           // max coarse buckets (1024 nodes each)
#define CSH 10               // coarse shift (1024 nodes)
#define HEPB 4096            // edges per fine-hist block
#define HT 512               // threads for fine-hist
#define CEPB 2048            // edges per coarse-part block
#define CT 256               // threads for coarse-part
#define CAP 2048             // k_agg chunk capacity (fine bucket mean ~1024)
#define CAPF 2048            // k_fpart chunk capacity
#define MAXCH 10             // y-grid for k_fpart (stride loop covers overflow)
#define AGG_T 512            // k_agg threads: 2 half-groups x 4 lanes per node

__device__ __forceinline__ unsigned f2bf_rne(float f) {
    unsigned u = __float_as_uint(f);
    return (u + 0x7FFFu + ((u >> 16) & 1u)) >> 16;
}
__device__ __forceinline__ float bf2f(unsigned h) {
    return __uint_as_float(h << 16);
}

// ---- Pass G: Y = X @ W, packed to bf16 (row = 16 uints = 64 B = 1 line) ----
__global__ __launch_bounds__(256) void k_gemm(const float* __restrict__ X,
                                              const float* __restrict__ W,
                                              unsigned* __restrict__ Y,
                                              int n_nodes) {
    __shared__ float Wlds[N_DIM * N_DIM];
    const int t = threadIdx.x;
    for (int i = t; i < N_DIM * N_DIM; i += 256) Wlds[i] = W[i];
    __syncthreads();

    const int r = blockIdx.x * 256 + t;
    if (r >= n_nodes) return;

    float x[N_DIM];
    const float4* xr = (const float4*)(X + (size_t)r * N_DIM);
#pragma unroll
    for (int i = 0; i < N_DIM / 4; ++i) {
        float4 v = xr[i];
        x[4 * i + 0] = v.x; x[4 * i + 1] = v.y;
        x[4 * i + 2] = v.z; x[4 * i + 3] = v.w;
    }
    float acc[N_DIM];
#pragma unroll
    for (int c = 0; c < N_DIM; ++c) acc[c] = 0.0f;
#pragma unroll
    for (int k = 0; k < N_DIM; ++k) {
        const float xk = x[k];
#pragma unroll
        for (int c = 0; c < N_DIM; ++c)
            acc[c] = fmaf(xk, Wlds[k * N_DIM + c], acc[c]);
    }
    unsigned yp[16];
#pragma unroll
    for (int q = 0; q < 16; ++q)
        yp[q] = f2bf_rne(acc[2 * q]) | (f2bf_rne(acc[2 * q + 1]) << 16);
    uint4* yr = (uint4*)(Y + (size_t)r * 16);
#pragma unroll
    for (int i = 0; i < 4; ++i)
        yr[i] = make_uint4(yp[4 * i], yp[4 * i + 1], yp[4 * i + 2], yp[4 * i + 3]);
}

// ---- Fine histogram (1563 bins) with LDS pre-aggregation ----
__global__ __launch_bounds__(HT) void k_fhist(const int* __restrict__ dst,
                                              int* __restrict__ gcount,
                                              int n_edges, int nb) {
    __shared__ int h[NB_MAX];
    const int t = threadIdx.x;
    for (int i = t; i < nb; i += HT) h[i] = 0;
    __syncthreads();
    const int start = blockIdx.x * HEPB;
#pragma unroll
    for (int k = 0; k < HEPB / HT; ++k) {
        int e = start + t + k * HT;
        if (e < n_edges) atomicAdd(&h[dst[e] >> NPB_SHIFT], 1);
    }
    __syncthreads();
    for (int i = t; i < nb; i += HT) {
        int c = h[i];
        if (c) atomicAdd(&gcount[i], c);
    }
}

// ---- Scan fine counts -> base/cursorF; derive coarse cursors; pad base ----
__global__ __launch_bounds__(1024) void k_bscan(const int* __restrict__ gcount,
                                                int* __restrict__ base,
                                                int* __restrict__ cursorF,
                                                int* __restrict__ cursorC,
                                                int nb, int ncoarse) {
    __shared__ int sc[1024];
    const int t = threadIdx.x;
    const int i0 = 2 * t, i1 = 2 * t + 1;
    int v0 = (i0 < nb) ? gcount[i0] : 0;
    int v1 = (i1 < nb) ? gcount[i1] : 0;
    int s = v0 + v1;
    sc[t] = s;
    __syncthreads();
    for (int off = 1; off < 1024; off <<= 1) {
        int x = (t >= off) ? sc[t - off] : 0;
        __syncthreads();
        sc[t] += x;
        __syncthreads();
    }
    int ex = sc[t] - s;
    if (i0 < nb) { base[i0] = ex;      cursorF[i0] = ex; }
    if (i1 < nb) { base[i1] = ex + v0; cursorF[i1] = ex + v0; }
    const int total = sc[1023];
    // pad base[nb .. 16*ncoarse] with total (for coarse range lookups)
    for (int i = nb + t; i <= 16 * ncoarse; i += 1024) base[i] = total;
    // coarse cursor: exclusive scan at fine index 16c == sc[8c-1]
    if (t < ncoarse) cursorC[t] = (t == 0) ? 0 : sc[8 * t - 1];
}

// ---- Coarse partition (98 bins): tmp[..] = src(17b) | dstLocal10<<17 ----
__global__ __launch_bounds__(CT) void k_cpart(const int* __restrict__ src,
                                              const int* __restrict__ dst,
                                              int* __restrict__ cursorC,
                                              int* __restrict__ tmp,
                                              int n_edges, int ncoarse) {
    __shared__ int h[NC_MAX];
    __shared__ int gb[NC_MAX];
    const int t = threadIdx.x;
    if (t < NC_MAX) h[t] = 0;
    __syncthreads();
    const int start = blockIdx.x * CEPB;

    int vw[CEPB / CT], cw[CEPB / CT], rw[CEPB / CT];
#pragma unroll
    for (int k = 0; k < CEPB / CT; ++k) {
        int e = start + t + k * CT;
        if (e < n_edges) {
            int d = dst[e];
            int c = d >> CSH;
            cw[k] = c;
            vw[k] = src[e] | ((d & 1023) << 17);
            rw[k] = atomicAdd(&h[c], 1);
        } else {
            cw[k] = -1;
        }
    }
    __syncthreads();
    if (t < ncoarse) {
        int c = h[t];
        gb[t] = c ? atomicAdd(&cursorC[t], c) : 0;
    }
    __syncthreads();
#pragma unroll
    for (int k = 0; k < CEPB / CT; ++k)
        if (cw[k] >= 0) tmp[gb[cw[k]] + rw[k]] = vw[k];
}

// ---- Fine refine: per coarse chunk, sort into 16 fine bins, coalesced out ----
__global__ __launch_bounds__(256) void k_fpart(const int* __restrict__ base,
                                               const int* __restrict__ tmp,
                                               int* __restrict__ cursorF,
                                               int* __restrict__ pairs,
                                               int ncoarse) {
    __shared__ int sp[CAPF];
    __shared__ int sbin[CAPF];
    __shared__ int cnt[16], lstart[16], cur[16], gpos[16];
    const int t = threadIdx.x;
    const int c = blockIdx.x;
    const int s0 = base[16 * c];
    const int s1 = base[16 * c + 16];

    for (int chunk = blockIdx.y; s0 + chunk * CAPF < s1; chunk += gridDim.y) {
        const int start = s0 + chunk * CAPF;
        const int n = min(CAPF, s1 - start);
        if (t < 16) cnt[t] = 0;
        __syncthreads();
        for (int i = t; i < n; i += 256) {
            int p = tmp[start + i];
            sp[i] = p;
            atomicAdd(&cnt[(p >> 23) & 15], 1);
        }
        __syncthreads();
        if (t == 0) {
            int run = 0;
            for (int f = 0; f < 16; ++f) { lstart[f] = run; cur[f] = run; run += cnt[f]; }
        }
        __syncthreads();
        for (int i = t; i < n; i += 256) {
            int p = sp[i];
            int f = (p >> 23) & 15;
            int r = atomicAdd(&cur[f], 1);
            sbin[r] = (p & 0x7FFFFF) | (f << 24);   // keep src|dl6, tag f
        }
        __syncthreads();
        if (t < 16) gpos[t] = cnt[t] ? atomicAdd(&cursorF[16 * c + t], cnt[t]) : 0;
        __syncthreads();
        for (int i = t; i < n; i += 256) {
            int e = sbin[i];
            int f = (e >> 24) & 15;
            pairs[gpos[f] + (i - lstart[f])] = e & 0x7FFFFF;
        }
        __syncthreads();
    }
}

// ---- Pass 2: per-bucket LOCAL counting-sort + register accumulation ----
// 512 threads: node nl = (t>>2)>>1, half = (t>>2)&1; each half-group takes
// half the node's segment -> balanced, 2x gather parallelism, full occupancy.
__device__ __forceinline__ void addv(float* acc, uint4 v) {
    acc[0] += bf2f(v.x & 0xFFFFu); acc[1] += bf2f(v.x >> 16);
    acc[2] += bf2f(v.y & 0xFFFFu); acc[3] += bf2f(v.y >> 16);
    acc[4] += bf2f(v.z & 0xFFFFu); acc[5] += bf2f(v.z >> 16);
    acc[6] += bf2f(v.w & 0xFFFFu); acc[7] += bf2f(v.w >> 16);
}

__global__ __launch_bounds__(AGG_T) void k_agg(const uint4* __restrict__ Y4,
                                               const int* __restrict__ base,
                                               const int* __restrict__ pairs,
                                               float* __restrict__ out,
                                               int n_nodes) {
    __shared__ int sp[CAP];
    __shared__ int sbin[CAP];
    __shared__ int cnt[NPB];
    __shared__ int cst[NPB];
    __shared__ int cur[NPB];
    __shared__ float accL[NPB][N_DIM + 1];

    const int t = threadIdx.x;
    const int b = blockIdx.x;
    const int e0 = base[b];
    const int e1 = base[b + 1];
    const int g = t >> 2;          // 0..127
    const int nl = g >> 1;         // local node 0..63
    const int half = g & 1;
    const int l = t & 3;           // quarter-row (16 B)

    float acc[8];
#pragma unroll
    for (int i = 0; i < 8; ++i) acc[i] = 0.0f;

    for (int cbase = e0; cbase < e1; cbase += CAP) {
        const int n = min(CAP, e1 - cbase);
        if (t < NPB) cnt[t] = 0;
        __syncthreads();
        for (int i = t; i < n; i += AGG_T) {
            int p = pairs[cbase + i];
            sp[i] = p;
            atomicAdd(&cnt[p >> 17], 1);
        }
        __syncthreads();
        // inclusive scan of 64 counts by wave 0 (no block barriers inside)
        if (t < 64) {
            int c = cnt[t];
#pragma unroll
            for (int off = 1; off < 64; off <<= 1) {
                int u = __shfl_up(c, off, 64);
                if (t >= off) c += u;
            }
            cst[t] = c;
            cur[t] = c - cnt[t];
        }
        __syncthreads();
        for (int i = t; i < n; i += AGG_T) {
            int p = sp[i];
            int r = atomicAdd(&cur[p >> 17], 1);
            sbin[r] = p & 0x1FFFF;
        }
        __syncthreads();
        // each half-group consumes half its node's segment; 4 gathers in flight
        const int sEnd = cst[nl];
        const int len = cnt[nl];
        const int sStart = sEnd - len;
        const int h0 = (len + 1) >> 1;
        const int ms = sStart + half * h0;
        const int me = half ? sEnd : (sStart + h0);
        for (int e = ms; e < me; e += 4) {
            const int m = me - e;
            int i0 = sbin[e];
            int i1 = sbin[e + ((m > 1) ? 1 : 0)];
            int i2 = sbin[e + ((m > 2) ? 2 : 0)];
            int i3 = sbin[e + ((m > 3) ? 3 : 0)];
            uint4 v0 = Y4[(size_t)i0 * 4 + l];
            uint4 v1 = Y4[(size_t)i1 * 4 + l];
            uint4 v2 = Y4[(size_t)i2 * 4 + l];
            uint4 v3 = Y4[(size_t)i3 * 4 + l];
            addv(acc, v0);
            if (m > 1) addv(acc, v1);
            if (m > 2) addv(acc, v2);
            if (m > 3) addv(acc, v3);
        }
        __syncthreads();
    }

    // combine halves via LDS
    if (half == 0) {
#pragma unroll
        for (int i = 0; i < 8; ++i) accL[nl][8 * l + i] = acc[i];
    }
    __syncthreads();
    if (half == 1) {
        const int node = b * NPB + nl;
        if (node < n_nodes) {
            float4 o0 = make_float4(accL[nl][8 * l + 0] + acc[0],
                                    accL[nl][8 * l + 1] + acc[1],
                                    accL[nl][8 * l + 2] + acc[2],
                                    accL[nl][8 * l + 3] + acc[3]);
            float4 o1 = make_float4(accL[nl][8 * l + 4] + acc[4],
                                    accL[nl][8 * l + 5] + acc[5],
                                    accL[nl][8 * l + 6] + acc[6],
                                    accL[nl][8 * l + 7] + acc[7]);
            ((float4*)out)[(size_t)node * 8 + 2 * l] = o0;
            ((float4*)out)[(size_t)node * 8 + 2 * l + 1] = o1;
        }
    }
}

extern "C" void kernel_launch(void* const* d_in, const int* in_sizes, int n_in,
                              void* d_out, int out_size, void* d_ws, size_t ws_size,
                              hipStream_t stream) {
    const float* X   = (const float*)d_in[0];
    const float* W   = (const float*)d_in[1];
    const int*   src = (const int*)d_in[2];
    const int*   dst = (const int*)d_in[3];
    float* out = (float*)d_out;

    const int n_nodes = in_sizes[0] / N_DIM;
    const int n_edges = in_sizes[2];
    const int nb = (n_nodes + NPB - 1) / NPB;        // 1563 fine buckets
    const int ncoarse = (nb + 15) / 16;              // 98 coarse buckets

    // workspace layout
    unsigned* Y  = (unsigned*)d_ws;                   // n_nodes*16 uints (6.4 MB)
    int* gcount  = (int*)(Y + (size_t)n_nodes * 16);  // NB_MAX
    int* base    = gcount + NB_MAX;                   // NB_MAX + 32 (padded)
    int* cursorF = base + NB_MAX + 32;                // NB_MAX
    int* cursorC = cursorF + NB_MAX;                  // NC_MAX
    int* tmp     = cursorC + NC_MAX;                  // n_edges
    int* pairs   = tmp + n_edges;                     // n_edges

    hipMemsetAsync(gcount, 0, (size_t)nb * sizeof(int), stream);

    const int nblk_h = (n_edges + HEPB - 1) / HEPB;   // 391
    const int nblk_c = (n_edges + CEPB - 1) / CEPB;   // 782
    k_gemm<<<(n_nodes + 255) / 256, 256, 0, stream>>>(X, W, Y, n_nodes);
    k_fhist<<<nblk_h, HT, 0, stream>>>(dst, gcount, n_edges, nb);
    k_bscan<<<1, 1024, 0, stream>>>(gcount, base, cursorF, cursorC, nb, ncoarse);
    k_cpart<<<nblk_c, CT, 0, stream>>>(src, dst, cursorC, tmp, n_edges, ncoarse);
    k_fpart<<<dim3(ncoarse, MAXCH), 256, 0, stream>>>(base, tmp, cursorF, pairs, ncoarse);
    k_agg<<<nb, AGG_T, 0, stream>>>((const uint4*)Y, base, pairs, out, n_nodes);
}

// Round 10
// 131.387 us; speedup vs baseline: 1.2223x; 1.2223x over previous
//
#include <hip/hip_runtime.h>

#define N_DIM 32
#define NPB 64               // fine bucket: nodes per bucket
#define NB_FINE_MAX 2048     // max fine buckets
#define NC_MAX 128           // max coarse buckets
#define CSH 10               // coarse bucket = 1024 nodes
#define CAPC 18432           // tmp slots per coarse bucket (mean 16327, +16 sigma)
#define CAPFINE 1280         // pairs slots per fine bucket (mean 1024, +8 sigma)
#define CEPB 4096            // edges per coarse-part block
#define CT 512
#define CAPF 2048            // fpart chunk
#define MAXCH 10             // fpart y-grid
#define CAP 2048             // agg chunk

__device__ __forceinline__ unsigned f2bf_rne(float f) {
    unsigned u = __float_as_uint(f);
    return (u + 0x7FFFu + ((u >> 16) & 1u)) >> 16;
}
__device__ __forceinline__ float bf2f(unsigned h) {
    return __uint_as_float(h << 16);
}

// ---- Pass G: Y = X @ W -> bf16 rows (64 B = 1 line); block 0 zeroes cursors ----
__global__ __launch_bounds__(256) void k_gemm(const float* __restrict__ X,
                                              const float* __restrict__ W,
                                              unsigned* __restrict__ Y,
                                              int* __restrict__ cursors,  // NC_MAX + NB_FINE_MAX
                                              int n_nodes) {
    __shared__ float Wlds[N_DIM * N_DIM];
    const int t = threadIdx.x;
    if (blockIdx.x == 0)
        for (int i = t; i < NC_MAX + NB_FINE_MAX; i += 256) cursors[i] = 0;
    for (int i = t; i < N_DIM * N_DIM; i += 256) Wlds[i] = W[i];
    __syncthreads();

    const int r = blockIdx.x * 256 + t;
    if (r >= n_nodes) return;

    float x[N_DIM];
    const float4* xr = (const float4*)(X + (size_t)r * N_DIM);
#pragma unroll
    for (int i = 0; i < N_DIM / 4; ++i) {
        float4 v = xr[i];
        x[4 * i + 0] = v.x; x[4 * i + 1] = v.y;
        x[4 * i + 2] = v.z; x[4 * i + 3] = v.w;
    }
    float acc[N_DIM];
#pragma unroll
    for (int c = 0; c < N_DIM; ++c) acc[c] = 0.0f;
#pragma unroll
    for (int k = 0; k < N_DIM; ++k) {
        const float xk = x[k];
#pragma unroll
        for (int c = 0; c < N_DIM; ++c)
            acc[c] = fmaf(xk, Wlds[k * N_DIM + c], acc[c]);
    }
    unsigned yp[16];
#pragma unroll
    for (int q = 0; q < 16; ++q)
        yp[q] = f2bf_rne(acc[2 * q]) | (f2bf_rne(acc[2 * q + 1]) << 16);
    uint4* yr = (uint4*)(Y + (size_t)r * 16);
#pragma unroll
    for (int i = 0; i < 4; ++i)
        yr[i] = make_uint4(yp[4 * i], yp[4 * i + 1], yp[4 * i + 2], yp[4 * i + 3]);
}

// ---- Coarse partition into fixed-cap tmp segments; val = src17 | dl10<<17 ----
__global__ __launch_bounds__(CT) void k_cpart(const int* __restrict__ src,
                                              const int* __restrict__ dst,
                                              int* __restrict__ cursorC0,
                                              int* __restrict__ tmp,
                                              int n_edges, int ncoarse) {
    __shared__ int h[NC_MAX];
    __shared__ int gb[NC_MAX];
    const int t = threadIdx.x;
    if (t < NC_MAX) h[t] = 0;
    __syncthreads();
    const int start = blockIdx.x * CEPB;

    int vw[CEPB / CT], cw[CEPB / CT], rw[CEPB / CT];
#pragma unroll
    for (int k = 0; k < CEPB / CT; ++k) {
        int e = start + t + k * CT;
        if (e < n_edges) {
            int d = dst[e];
            int c = d >> CSH;
            cw[k] = c;
            vw[k] = src[e] | ((d & 1023) << 17);
            rw[k] = atomicAdd(&h[c], 1);
        } else {
            cw[k] = -1;
        }
    }
    __syncthreads();
    if (t < ncoarse) {
        int c = h[t];
        gb[t] = c ? atomicAdd(&cursorC0[t], c) : 0;
    }
    __syncthreads();
#pragma unroll
    for (int k = 0; k < CEPB / CT; ++k)
        if (cw[k] >= 0) {
            int idx = gb[cw[k]] + rw[k];
            if (idx < CAPC) tmp[cw[k] * CAPC + idx] = vw[k];
        }
}

// ---- Fine refine: 16 bins per coarse chunk, rank-reuse, direct global write ----
__global__ __launch_bounds__(256) void k_fpart(const int* __restrict__ tmp,
                                               const int* __restrict__ cursorC0,
                                               int* __restrict__ cursorF0,
                                               int* __restrict__ pairs,
                                               int ncoarse) {
    __shared__ int cnt[16], gpos[16];
    const int t = threadIdx.x;
    const int c = blockIdx.x;
    const int lenC = min(cursorC0[c], CAPC);

    for (int chunk = blockIdx.y; chunk * CAPF < lenC; chunk += gridDim.y) {
        const int start = chunk * CAPF;
        const int n = min(CAPF, lenC - start);
        if (t < 16) cnt[t] = 0;
        __syncthreads();
        int pv[CAPF / 256], rv[CAPF / 256];
#pragma unroll
        for (int k = 0; k < CAPF / 256; ++k) {
            int i = t + k * 256;
            if (i < n) {
                int p = tmp[c * CAPC + start + i];
                pv[k] = p;
                rv[k] = atomicAdd(&cnt[(p >> 23) & 15], 1);
            } else {
                pv[k] = -1;
            }
        }
        __syncthreads();
        if (t < 16) gpos[t] = cnt[t] ? atomicAdd(&cursorF0[16 * c + t], cnt[t]) : 0;
        __syncthreads();
#pragma unroll
        for (int k = 0; k < CAPF / 256; ++k) {
            if (pv[k] >= 0) {
                int p = pv[k];
                int f = (p >> 23) & 15;
                int idx = gpos[f] + rv[k];
                if (idx < CAPFINE)
                    pairs[(size_t)(16 * c + f) * CAPFINE + idx] = p & 0x7FFFFF;
            }
        }
        __syncthreads();
    }
}

// ---- Aggregate: per-fine-bucket counting-sort (rank-reuse) + reg accumulate ----
__device__ __forceinline__ void addv(float* acc, uint4 v) {
    acc[0] += bf2f(v.x & 0xFFFFu); acc[1] += bf2f(v.x >> 16);
    acc[2] += bf2f(v.y & 0xFFFFu); acc[3] += bf2f(v.y >> 16);
    acc[4] += bf2f(v.z & 0xFFFFu); acc[5] += bf2f(v.z >> 16);
    acc[6] += bf2f(v.w & 0xFFFFu); acc[7] += bf2f(v.w >> 16);
}

__global__ __launch_bounds__(256) void k_agg(const uint4* __restrict__ Y4,
                                             const int* __restrict__ cursorF0,
                                             const int* __restrict__ pairs,
                                             float* __restrict__ out,
                                             int n_nodes) {
    __shared__ int sbin[CAP];
    __shared__ int cnt[NPB];
    __shared__ int cst[NPB];
    __shared__ int excl[NPB];

    const int t = threadIdx.x;
    const int b = blockIdx.x;
    const int len = min(cursorF0[b], CAPFINE);
    const size_t segbase = (size_t)b * CAPFINE;
    const int g = t >> 2;          // local node 0..63
    const int l = t & 3;           // quarter-row (16 B)

    float acc[8];
#pragma unroll
    for (int i = 0; i < 8; ++i) acc[i] = 0.0f;

    for (int cbase = 0; cbase < len; cbase += CAP) {
        const int n = min(CAP, len - cbase);
        if (t < NPB) cnt[t] = 0;
        __syncthreads();
        int pv[CAP / 256], rv[CAP / 256];
#pragma unroll
        for (int k = 0; k < CAP / 256; ++k) {
            int i = t + k * 256;
            if (i < n) {
                int p = pairs[segbase + cbase + i];
                pv[k] = p;
                rv[k] = atomicAdd(&cnt[p >> 17], 1);
            } else {
                pv[k] = -1;
            }
        }
        __syncthreads();
        // inclusive scan of 64 counts in wave 0
        if (t < 64) {
            int c0 = cnt[t];
            int c = c0;
#pragma unroll
            for (int off = 1; off < 64; off <<= 1) {
                int u = __shfl_up(c, off, 64);
                if (t >= off) c += u;
            }
            cst[t] = c;
            excl[t] = c - c0;
        }
        __syncthreads();
#pragma unroll
        for (int k = 0; k < CAP / 256; ++k) {
            if (pv[k] >= 0) {
                int p = pv[k];
                sbin[excl[p >> 17] + rv[k]] = p & 0x1FFFF;
            }
        }
        __syncthreads();
        // each group consumes its node's segment; 4 gathers in flight
        const int s1 = cst[g];
        const int s0 = s1 - cnt[g];
        for (int e = s0; e < s1; e += 4) {
            const int m = s1 - e;
            int i0 = sbin[e];
            int i1 = sbin[e + ((m > 1) ? 1 : 0)];
            int i2 = sbin[e + ((m > 2) ? 2 : 0)];
            int i3 = sbin[e + ((m > 3) ? 3 : 0)];
            uint4 v0 = Y4[(size_t)i0 * 4 + l];
            uint4 v1 = Y4[(size_t)i1 * 4 + l];
            uint4 v2 = Y4[(size_t)i2 * 4 + l];
            uint4 v3 = Y4[(size_t)i3 * 4 + l];
            addv(acc, v0);
            if (m > 1) addv(acc, v1);
            if (m > 2) addv(acc, v2);
            if (m > 3) addv(acc, v3);
        }
        __syncthreads();
    }

    const int node = b * NPB + g;
    if (node < n_nodes) {
        ((float4*)out)[(size_t)node * 8 + 2 * l] =
            make_float4(acc[0], acc[1], acc[2], acc[3]);
        ((float4*)out)[(size_t)node * 8 + 2 * l + 1] =
            make_float4(acc[4], acc[5], acc[6], acc[7]);
    }
}

extern "C" void kernel_launch(void* const* d_in, const int* in_sizes, int n_in,
                              void* d_out, int out_size, void* d_ws, size_t ws_size,
                              hipStream_t stream) {
    const float* X   = (const float*)d_in[0];
    const float* W   = (const float*)d_in[1];
    const int*   src = (const int*)d_in[2];
    const int*   dst = (const int*)d_in[3];
    float* out = (float*)d_out;

    const int n_nodes = in_sizes[0] / N_DIM;
    const int n_edges = in_sizes[2];
    const int nb = (n_nodes + NPB - 1) / NPB;        // 1563 fine buckets
    const int ncoarse = (n_nodes + 1023) / 1024;     // 98 coarse buckets

    // workspace layout
    unsigned* Y   = (unsigned*)d_ws;                  // n_nodes*16 uints (6.4 MB)
    int* cursorC0 = (int*)(Y + (size_t)n_nodes * 16); // NC_MAX
    int* cursorF0 = cursorC0 + NC_MAX;                // NB_FINE_MAX
    int* tmp      = cursorF0 + NB_FINE_MAX;           // ncoarse * CAPC (7.2 MB)
    int* pairs    = tmp + (size_t)ncoarse * CAPC;     // nb * CAPFINE (8.0 MB)

    const int nblk_g = (n_nodes + 255) / 256;         // 391
    const int nblk_c = (n_edges + CEPB - 1) / CEPB;   // 391

    k_gemm<<<nblk_g, 256, 0, stream>>>(X, W, Y, cursorC0, n_nodes);
    k_cpart<<<nblk_c, CT, 0, stream>>>(src, dst, cursorC0, tmp, n_edges, ncoarse);
    k_fpart<<<dim3(ncoarse, MAXCH), 256, 0, stream>>>(tmp, cursorC0, cursorF0, pairs, ncoarse);
    k_agg<<<nb, 256, 0, stream>>>((const uint4*)Y, cursorF0, pairs, out, n_nodes);
}

// Round 11
// 126.329 us; speedup vs baseline: 1.2712x; 1.0400x over previous
//
#include <hip/hip_runtime.h>

#define N_DIM 32
#define NPB 64               // fine bucket: nodes per bucket
#define NB_FINE_MAX 2048     // max fine buckets
#define NC_MAX 128           // max coarse buckets
#define CSH 10               // coarse bucket = 1024 nodes
#define CAPC 18432           // tmp slots per coarse bucket (mean 16384, +16 sigma)
#define CAPFINE 1280         // pairs slots per fine bucket (mean 1024, +8 sigma)
#define CEPB 4096            // edges per coarse-part block
#define FT 512               // fused kernel threads
#define GROWS 512            // gemm rows per block (FT threads, 1 row/thread)
#define CAPF 2048            // fpart chunk
#define MAXCH 10             // fpart y-grid

__device__ __forceinline__ unsigned f2bf_rne(float f) {
    unsigned u = __float_as_uint(f);
    return (u + 0x7FFFu + ((u >> 16) & 1u)) >> 16;
}
__device__ __forceinline__ float bf2f(unsigned h) {
    return __uint_as_float(h << 16);
}

// ---- Fused pass: blocks [0,nblk_g) = GEMM (Y=X@W -> bf16 rows);
// ----             blocks [nblk_g,..) = coarse partition (no dependence). ----
__global__ __launch_bounds__(FT) void k_fused(const float* __restrict__ X,
                                              const float* __restrict__ W,
                                              unsigned* __restrict__ Y,
                                              const int* __restrict__ src,
                                              const int* __restrict__ dst,
                                              int* __restrict__ cursorC0,
                                              int* __restrict__ tmp,
                                              int n_nodes, int n_edges,
                                              int ncoarse, int nblk_g) {
    __shared__ float Wlds[N_DIM * N_DIM];
    __shared__ int h[NC_MAX];
    __shared__ int gb[NC_MAX];
    const int t = threadIdx.x;

    if (blockIdx.x < nblk_g) {
        // ---------------- GEMM half ----------------
        for (int i = t; i < N_DIM * N_DIM; i += FT) Wlds[i] = W[i];
        __syncthreads();
        const int r = blockIdx.x * GROWS + t;
        if (r >= n_nodes) return;

        float x[N_DIM];
        const float4* xr = (const float4*)(X + (size_t)r * N_DIM);
#pragma unroll
        for (int i = 0; i < N_DIM / 4; ++i) {
            float4 v = xr[i];
            x[4 * i + 0] = v.x; x[4 * i + 1] = v.y;
            x[4 * i + 2] = v.z; x[4 * i + 3] = v.w;
        }
        float acc[N_DIM];
#pragma unroll
        for (int c = 0; c < N_DIM; ++c) acc[c] = 0.0f;
#pragma unroll
        for (int k = 0; k < N_DIM; ++k) {
            const float xk = x[k];
#pragma unroll
            for (int c = 0; c < N_DIM; ++c)
                acc[c] = fmaf(xk, Wlds[k * N_DIM + c], acc[c]);
        }
        unsigned yp[16];
#pragma unroll
        for (int q = 0; q < 16; ++q)
            yp[q] = f2bf_rne(acc[2 * q]) | (f2bf_rne(acc[2 * q + 1]) << 16);
        uint4* yr = (uint4*)(Y + (size_t)r * 16);
#pragma unroll
        for (int i = 0; i < 4; ++i)
            yr[i] = make_uint4(yp[4 * i], yp[4 * i + 1],
                               yp[4 * i + 2], yp[4 * i + 3]);
    } else {
        // ---------------- coarse-partition half ----------------
        if (t < NC_MAX) h[t] = 0;
        __syncthreads();
        const int start = (blockIdx.x - nblk_g) * CEPB;

        int vw[CEPB / FT], cw[CEPB / FT], rw[CEPB / FT];
#pragma unroll
        for (int k = 0; k < CEPB / FT; ++k) {
            int e = start + t + k * FT;
            if (e < n_edges) {
                int d = dst[e];
                int c = d >> CSH;
                cw[k] = c;
                vw[k] = src[e] | ((d & 1023) << 17);
                rw[k] = atomicAdd(&h[c], 1);
            } else {
                cw[k] = -1;
            }
        }
        __syncthreads();
        if (t < ncoarse) {
            int c = h[t];
            gb[t] = c ? atomicAdd(&cursorC0[t], c) : 0;
        }
        __syncthreads();
#pragma unroll
        for (int k = 0; k < CEPB / FT; ++k)
            if (cw[k] >= 0) {
                int idx = gb[cw[k]] + rw[k];
                if (idx < CAPC) tmp[cw[k] * CAPC + idx] = vw[k];
            }
    }
}

// ---- Fine refine: 16 bins per coarse chunk, rank-reuse, direct global write ----
__global__ __launch_bounds__(256) void k_fpart(const int* __restrict__ tmp,
                                               const int* __restrict__ cursorC0,
                                               int* __restrict__ cursorF0,
                                               int* __restrict__ pairs,
                                               int ncoarse) {
    __shared__ int cnt[16], gpos[16];
    const int t = threadIdx.x;
    const int c = blockIdx.x;
    const int lenC = min(cursorC0[c], CAPC);

    for (int chunk = blockIdx.y; chunk * CAPF < lenC; chunk += gridDim.y) {
        const int start = chunk * CAPF;
        const int n = min(CAPF, lenC - start);
        if (t < 16) cnt[t] = 0;
        __syncthreads();
        int pv[CAPF / 256], rv[CAPF / 256];
#pragma unroll
        for (int k = 0; k < CAPF / 256; ++k) {
            int i = t + k * 256;
            if (i < n) {
                int p = tmp[c * CAPC + start + i];
                pv[k] = p;
                rv[k] = atomicAdd(&cnt[(p >> 23) & 15], 1);
            } else {
                pv[k] = -1;
            }
        }
        __syncthreads();
        if (t < 16) gpos[t] = cnt[t] ? atomicAdd(&cursorF0[16 * c + t], cnt[t]) : 0;
        __syncthreads();
#pragma unroll
        for (int k = 0; k < CAPF / 256; ++k) {
            if (pv[k] >= 0) {
                int p = pv[k];
                int f = (p >> 23) & 15;
                int idx = gpos[f] + rv[k];
                if (idx < CAPFINE)
                    pairs[(size_t)(16 * c + f) * CAPFINE + idx] = p & 0x7FFFFF;
            }
        }
        __syncthreads();
    }
}

// ---- Aggregate: single-pass per-fine-bucket counting-sort + reg accumulate ----
__device__ __forceinline__ void addv(float* acc, uint4 v) {
    acc[0] += bf2f(v.x & 0xFFFFu); acc[1] += bf2f(v.x >> 16);
    acc[2] += bf2f(v.y & 0xFFFFu); acc[3] += bf2f(v.y >> 16);
    acc[4] += bf2f(v.z & 0xFFFFu); acc[5] += bf2f(v.z >> 16);
    acc[6] += bf2f(v.w & 0xFFFFu); acc[7] += bf2f(v.w >> 16);
}

__global__ __launch_bounds__(256) void k_agg(const uint4* __restrict__ Y4,
                                             const int* __restrict__ cursorF0,
                                             const int* __restrict__ pairs,
                                             float* __restrict__ out,
                                             int n_nodes) {
    __shared__ int sbin[CAPFINE];
    __shared__ int cnt[NPB];
    __shared__ int cst[NPB];
    __shared__ int excl[NPB];

    const int t = threadIdx.x;
    const int b = blockIdx.x;
    const int len = min(cursorF0[b], CAPFINE);
    const size_t segbase = (size_t)b * CAPFINE;
    const int g = t >> 2;          // local node 0..63
    const int l = t & 3;           // quarter-row (16 B)

    if (t < NPB) cnt[t] = 0;
    __syncthreads();

    int pv[CAPFINE / 256], rv[CAPFINE / 256];
#pragma unroll
    for (int k = 0; k < CAPFINE / 256; ++k) {
        int i = t + k * 256;
        if (i < len) {
            int p = pairs[segbase + i];
            pv[k] = p;
            rv[k] = atomicAdd(&cnt[p >> 17], 1);
        } else {
            pv[k] = -1;
        }
    }
    __syncthreads();
    // inclusive scan of 64 counts in wave 0
    if (t < 64) {
        int c0 = cnt[t];
        int c = c0;
#pragma unroll
        for (int off = 1; off < 64; off <<= 1) {
            int u = __shfl_up(c, off, 64);
            if (t >= off) c += u;
        }
        cst[t] = c;
        excl[t] = c - c0;
    }
    __syncthreads();
#pragma unroll
    for (int k = 0; k < CAPFINE / 256; ++k) {
        if (pv[k] >= 0) {
            int p = pv[k];
            sbin[excl[p >> 17] + rv[k]] = p & 0x1FFFF;
        }
    }
    __syncthreads();

    float acc[8];
#pragma unroll
    for (int i = 0; i < 8; ++i) acc[i] = 0.0f;

    // each group consumes its node's segment; 4 gathers in flight
    const int s1 = cst[g];
    const int s0 = s1 - cnt[g];
    for (int e = s0; e < s1; e += 4) {
        const int m = s1 - e;
        int i0 = sbin[e];
        int i1 = sbin[e + ((m > 1) ? 1 : 0)];
        int i2 = sbin[e + ((m > 2) ? 2 : 0)];
        int i3 = sbin[e + ((m > 3) ? 3 : 0)];
        uint4 v0 = Y4[(size_t)i0 * 4 + l];
        uint4 v1 = Y4[(size_t)i1 * 4 + l];
        uint4 v2 = Y4[(size_t)i2 * 4 + l];
        uint4 v3 = Y4[(size_t)i3 * 4 + l];
        addv(acc, v0);
        if (m > 1) addv(acc, v1);
        if (m > 2) addv(acc, v2);
        if (m > 3) addv(acc, v3);
    }

    const int node = b * NPB + g;
    if (node < n_nodes) {
        ((float4*)out)[(size_t)node * 8 + 2 * l] =
            make_float4(acc[0], acc[1], acc[2], acc[3]);
        ((float4*)out)[(size_t)node * 8 + 2 * l + 1] =
            make_float4(acc[4], acc[5], acc[6], acc[7]);
    }
}

extern "C" void kernel_launch(void* const* d_in, const int* in_sizes, int n_in,
                              void* d_out, int out_size, void* d_ws, size_t ws_size,
                              hipStream_t stream) {
    const float* X   = (const float*)d_in[0];
    const float* W   = (const float*)d_in[1];
    const int*   src = (const int*)d_in[2];
    const int*   dst = (const int*)d_in[3];
    float* out = (float*)d_out;

    const int n_nodes = in_sizes[0] / N_DIM;
    const int n_edges = in_sizes[2];
    const int nb = (n_nodes + NPB - 1) / NPB;        // 1563 fine buckets
    const int ncoarse = (n_nodes + 1023) / 1024;     // 98 coarse buckets

    // workspace layout
    unsigned* Y   = (unsigned*)d_ws;                  // n_nodes*16 uints (6.4 MB)
    int* cursorC0 = (int*)(Y + (size_t)n_nodes * 16); // NC_MAX
    int* cursorF0 = cursorC0 + NC_MAX;                // NB_FINE_MAX
    int* tmp      = cursorF0 + NB_FINE_MAX;           // ncoarse * CAPC (7.2 MB)
    int* pairs    = tmp + (size_t)ncoarse * CAPC;     // nb * CAPFINE (8.0 MB)

    const int nblk_g = (n_nodes + GROWS - 1) / GROWS; // 196
    const int nblk_c = (n_edges + CEPB - 1) / CEPB;   // 391

    // zero both cursor arrays (8.7 KB)
    hipMemsetAsync(cursorC0, 0, (size_t)(NC_MAX + NB_FINE_MAX) * sizeof(int), stream);

    k_fused<<<nblk_g + nblk_c, FT, 0, stream>>>(X, W, Y, src, dst, cursorC0, tmp,
                                                n_nodes, n_edges, ncoarse, nblk_g);
    k_fpart<<<dim3(ncoarse, MAXCH), 256, 0, stream>>>(tmp, cursorC0, cursorF0,
                                                      pairs, ncoarse);
    k_agg<<<nb, 256, 0, stream>>>((const uint4*)Y, cursorF0, pairs, out, n_nodes);
}